// Round 8
// baseline (236.276 us; speedup 1.0000x reference)
//
#include <hip/hip_runtime.h>
#include <math.h>

namespace {

constexpr int D  = 128;
constexpr int H  = 8;
constexpr int TN = 64;
constexpr int K2_ITERS = 16;   // batches per k2 block

// lgkm-only barrier: does NOT drain vmcnt -> in-flight global_load_lds keeps flying
#define LGKM_BAR() do { asm volatile("s_waitcnt lgkmcnt(0)" ::: "memory"); \
                        __builtin_amdgcn_s_barrier(); } while (0)

__device__ __forceinline__ void gl_lds16(const float4* g, float* l) {
    __builtin_amdgcn_global_load_lds(
        (const __attribute__((address_space(1))) unsigned int*)(g),
        (__attribute__((address_space(3))) unsigned int*)(l), 16, 0, 0);
}
__device__ __forceinline__ void gl_lds4(const float* g, float* l) {
    __builtin_amdgcn_global_load_lds(
        (const __attribute__((address_space(1))) unsigned int*)(g),
        (__attribute__((address_space(3))) unsigned int*)(l), 4, 0, 0);
}

// d_ws layout (requires ws_size >= 34.6 MB):
//   N  [128][1024] f32, M [1024][128] f32, QS [B][1024] f32 (qk -> s in-place)

// ---------------- K0: precompute N and M (tiny) ----------------
__global__ __launch_bounds__(256)
void k0_nm(const float* __restrict__ WQ, const float* __restrict__ WK,
           const float* __restrict__ WV, const float* __restrict__ WO,
           float* __restrict__ Nmat, float* __restrict__ Mmat)
{
    const int t = blockIdx.x * 256 + threadIdx.x;   // 0..131071
    {
        const int k = t >> 10, col = t & 1023;
        const int h = col >> 7, d = col & 127;
        const float* wq = WQ + (size_t)k * D + h * 16;
        const float* wk = WK + (size_t)d * D + h * 16;
        float a = 0.f;
        #pragma unroll
        for (int j = 0; j < 16; ++j) a = fmaf(wq[j], wk[j], a);
        Nmat[t] = 0.25f * a;
    }
    {
        const int row = t >> 7, e = t & 127;
        const int h = row >> 7, d = row & 127;
        const float* wv = WV + (size_t)d * D + h * 16;
        const float* wo = WO + (size_t)(h * 16) * D + e;
        float a = 0.f;
        #pragma unroll
        for (int j = 0; j < 16; ++j) a = fmaf(wv[j], wo[(size_t)j * D], a);
        Mmat[t] = a;
    }
}

// ---------------- K1: qk = center @ N  (8 rows/block, r4-proven) ----------------
__global__ __launch_bounds__(256)
void k1_qk(const float* __restrict__ center, const float* __restrict__ Nmat,
           float* __restrict__ qk)
{
    __shared__ float c_lds[8 * 128];
    const int tid = threadIdx.x;
    const size_t rb = (size_t)blockIdx.x * 8;

    ((float4*)c_lds)[tid] = ((const float4*)(center + rb * D))[tid];
    __syncthreads();

    const float4* Np = (const float4*)Nmat + tid;
    float4 acc[8];
    #pragma unroll
    for (int r = 0; r < 8; ++r) acc[r] = make_float4(0.f, 0.f, 0.f, 0.f);

    float4 bufA[4], bufB[4];
    #pragma unroll
    for (int i = 0; i < 4; ++i) bufA[i] = Np[(size_t)i * 256];

    #pragma unroll
    for (int g = 0; g < 32; ++g) {
        float4* cur = (g & 1) ? bufB : bufA;
        float4* nxt = (g & 1) ? bufA : bufB;
        if (g < 31) {
            #pragma unroll
            for (int i = 0; i < 4; ++i) nxt[i] = Np[(size_t)(g * 4 + 4 + i) * 256];
        }
        #pragma unroll
        for (int i = 0; i < 4; ++i) {
            const int k = g * 4 + i;
            const float4 nv = cur[i];
            #pragma unroll
            for (int r = 0; r < 8; ++r) {
                const float cc = c_lds[r * 128 + k];
                acc[r].x = fmaf(cc, nv.x, acc[r].x);
                acc[r].y = fmaf(cc, nv.y, acc[r].y);
                acc[r].z = fmaf(cc, nv.z, acc[r].z);
                acc[r].w = fmaf(cc, nv.w, acc[r].w);
            }
        }
    }
    #pragma unroll
    for (int r = 0; r < 8; ++r)
        ((float4*)(qk + (rb + r) * 1024))[tid] = acc[r];
}

// ---------------- K2 v5: async double-buffered pipeline via global_load_lds ----------------
// LDS 75.3 KB -> 2 blocks/CU. Loop: sync(drain) -> issue next batch -> compute current.
__global__ __launch_bounds__(256)
void k2_stream(const float* __restrict__ center, const float* __restrict__ neighbors,
               float* __restrict__ qs /* in: qk, out: s (in-place per batch) */)
{
    __shared__ float nb_lds[2][TN * D];    // 2 x 32 KB; slot (t<<5)|(fc^(t&7)) holds (t,fc)
    __shared__ float qk_lds[2][H * D];     // 2 x 4 KB
    __shared__ float c_lds[2][D];          // 2 x 0.5 KB
    __shared__ float P_lds[TN][8];         // 2 KB
    __shared__ float red[4][2][8];         // 256 B

    const int tid = threadIdx.x;           // 0..255
    const int w   = tid >> 6;              // wave 0..3
    const int l   = tid & 63;
    const int b0  = blockIdx.x * K2_ITERS;

    // issue all async loads for one batch into buffer `buf`
    // nb: 32 chunks of 1KB (wave w -> chunks w*8..w*8+7), LDS linear, source pre-swizzled
    auto issue_batch = [&](int b, int buf) {
        const float4* gnb = (const float4*)(neighbors + (size_t)b * TN * D);
        #pragma unroll
        for (int i = 0; i < 8; ++i) {
            const int k  = w * 8 + i;
            const int fi = k * 64 + l;                                // linear LDS f4 slot
            const int gi = (fi & ~31) | ((fi & 31) ^ ((fi >> 5) & 7)); // inverse-swizzled src
            gl_lds16(gnb + gi, &nb_lds[buf][k * 256]);
        }
        if (w == 0) {
            const float4* qp = (const float4*)(qs + (size_t)b * 1024);
            #pragma unroll
            for (int m = 0; m < 4; ++m)
                gl_lds16(qp + m * 64 + l, &qk_lds[buf][m * 256]);
        } else if (w == 1) {
            const float* cb = center + (size_t)b * D;
            #pragma unroll
            for (int n = 0; n < 2; ++n)
                gl_lds4(cb + n * 64 + l, &c_lds[buf][n * 64]);
        }
    };

    int cur = 0;
    issue_batch(b0, 0);

    for (int j = 0; j < K2_ITERS; ++j) {
        const int b = b0 + j;
        float* qsb = qs + (size_t)b * 1024;

        __syncthreads();                   // drains vmcnt: buf[cur] fully landed
        if (j + 1 < K2_ITERS) issue_batch(b + 1, cur ^ 1);   // flies during compute

        const float* nbw = nb_lds[cur];
        const float* qkw = qk_lds[cur];
        const float* cw  = c_lds[cur];

        // ---- pass 1: wave w scores tokens w*16+(l&15); quarters q=l>>4 split d ----
        const int tq = l & 15;
        const int q  = l >> 4;
        const int t1 = w * 16 + tq;
        const int t1rb = t1 << 5;
        const int t1sw = t1 & 7;
        float sc[8];
        #pragma unroll
        for (int h = 0; h < 8; ++h) sc[h] = 0.f;
        #pragma unroll
        for (int jj = 0; jj < 8; ++jj) {
            // per-quarter jj rotation: the 4 concurrent kv addresses land on 4
            // distinct bank-quads (was 4-way conflict = the 7.5M cycles in r7)
            const int fc = q * 8 + ((jj + 2 * q) & 7);
            const float4 tv = ((const float4*)nbw)[t1rb | (fc ^ t1sw)];
            #pragma unroll
            for (int h = 0; h < 8; ++h) {
                const float4 kv = ((const float4*)qkw)[h * 32 + fc];
                sc[h] = fmaf(tv.x, kv.x, fmaf(tv.y, kv.y, fmaf(tv.z, kv.z, fmaf(tv.w, kv.w, sc[h]))));
            }
        }
        #pragma unroll
        for (int h = 0; h < 8; ++h) {      // combine the 4 d-quarters
            sc[h] += __shfl_xor(sc[h], 16);
            sc[h] += __shfl_xor(sc[h], 32);
        }

        // ---- center score s0[h] ----
        float s0[8];
        {
            const float cx = cw[2 * l], cy = cw[2 * l + 1];
            #pragma unroll
            for (int h = 0; h < 8; ++h) {
                const float2 qq = *reinterpret_cast<const float2*>(&qkw[h * 128 + 2 * l]);
                float v = qq.x * cx + qq.y * cy;
                #pragma unroll
                for (int off = 32; off >= 1; off >>= 1) v += __shfl_xor(v, off);
                s0[h] = v;
            }
        }

        // ---- softmax over 65 tokens (4-wave combine; lgkm-only barriers) ----
        float mw[8];
        #pragma unroll
        for (int h = 0; h < 8; ++h) {
            float m = sc[h];
            #pragma unroll
            for (int off = 8; off >= 1; off >>= 1) m = fmaxf(m, __shfl_xor(m, off));
            mw[h] = m;
        }
        if (l == 0) {
            #pragma unroll
            for (int h = 0; h < 8; ++h) red[w][0][h] = mw[h];
        }
        LGKM_BAR();

        float pmy[8], pctr[8], e0[8], sw_[8];
        #pragma unroll
        for (int h = 0; h < 8; ++h) {
            const float m = fmaxf(fmaxf(fmaxf(red[0][0][h], red[1][0][h]),
                                        fmaxf(red[2][0][h], red[3][0][h])), s0[h]);
            pmy[h] = __expf(sc[h] - m);
            e0[h]  = __expf(s0[h] - m);
            float s = pmy[h];
            #pragma unroll
            for (int off = 8; off >= 1; off >>= 1) s += __shfl_xor(s, off);
            sw_[h] = s;
        }
        if (l == 0) {
            #pragma unroll
            for (int h = 0; h < 8; ++h) red[w][1][h] = sw_[h];
        }
        LGKM_BAR();

        #pragma unroll
        for (int h = 0; h < 8; ++h) {
            const float inv = 1.0f / (red[0][1][h] + red[1][1][h] + red[2][1][h]
                                      + red[3][1][h] + e0[h]);
            pmy[h]  *= inv;
            pctr[h]  = e0[h] * inv;
        }
        if (l < 16) {
            *reinterpret_cast<float4*>(&P_lds[t1][0]) = make_float4(pmy[0], pmy[1], pmy[2], pmy[3]);
            *reinterpret_cast<float4*>(&P_lds[t1][4]) = make_float4(pmy[4], pmy[5], pmy[6], pmy[7]);
        }
        LGKM_BAR();

        // ---- pass 2: wave w owns f4 cols w*8..w*8+7; lanes split 64 tokens 8 ways ----
        const int cl  = l & 7;
        const int ti  = l >> 3;
        const int fc2 = w * 8 + cl;
        float4 acc[8];
        #pragma unroll
        for (int h = 0; h < 8; ++h) acc[h] = make_float4(0.f, 0.f, 0.f, 0.f);
        #pragma unroll
        for (int tt = 0; tt < 8; ++tt) {
            const int t2 = ti * 8 + tt;    // t2 & 7 == tt
            const float4 tv = ((const float4*)nbw)[(t2 << 5) | (fc2 ^ tt)];
            const float4 pa = *reinterpret_cast<const float4*>(&P_lds[t2][0]);
            const float4 pb = *reinterpret_cast<const float4*>(&P_lds[t2][4]);
            const float p8[8] = {pa.x, pa.y, pa.z, pa.w, pb.x, pb.y, pb.z, pb.w};
            #pragma unroll
            for (int h = 0; h < 8; ++h) {
                acc[h].x = fmaf(p8[h], tv.x, acc[h].x);
                acc[h].y = fmaf(p8[h], tv.y, acc[h].y);
                acc[h].z = fmaf(p8[h], tv.z, acc[h].z);
                acc[h].w = fmaf(p8[h], tv.w, acc[h].w);
            }
        }
        #pragma unroll
        for (int h = 0; h < 8; ++h) {
            #pragma unroll
            for (int off = 8; off <= 32; off <<= 1) {
                acc[h].x += __shfl_xor(acc[h].x, off);
                acc[h].y += __shfl_xor(acc[h].y, off);
                acc[h].z += __shfl_xor(acc[h].z, off);
                acc[h].w += __shfl_xor(acc[h].w, off);
            }
        }
        if (ti == 0) {                     // lanes 0..7: write cols fc2, + center seed
            const float4 cc = ((const float4*)cw)[fc2];
            #pragma unroll
            for (int h = 0; h < 8; ++h) {
                float4 o;
                o.x = acc[h].x + pctr[h] * cc.x;
                o.y = acc[h].y + pctr[h] * cc.y;
                o.z = acc[h].z + pctr[h] * cc.z;
                o.w = acc[h].w + pctr[h] * cc.w;
                *reinterpret_cast<float4*>(qsb + h * 128 + fc2 * 4) = o;
            }
        }
        cur ^= 1;
    }
}

// ---------------- K3: out = s @ M  (8 rows/block, r4-proven) ----------------
__global__ __launch_bounds__(256)
void k3_out(const float* __restrict__ qs, const float* __restrict__ Mmat,
            float* __restrict__ out)
{
    __shared__ float s_lds[8 * 1024];
    const int tid = threadIdx.x;
    const size_t rb = (size_t)blockIdx.x * 8;

    {
        const float4* sp = (const float4*)(qs + rb * 1024);
        #pragma unroll
        for (int i = 0; i < 8; ++i)
            ((float4*)s_lds)[i * 256 + tid] = sp[i * 256 + tid];
    }
    __syncthreads();

    const int cg = tid & 31;
    const int kg = tid >> 5;
    const int c4 = cg << 2;
    const int kbase = kg << 7;
    const int rot = kg << 2;

    float4 acc[8];
    #pragma unroll
    for (int r = 0; r < 8; ++r) acc[r] = make_float4(0.f, 0.f, 0.f, 0.f);

    const float4* Mp4 = (const float4*)Mmat;

    float4 bA[4], bB[4];
    #pragma unroll
    for (int i = 0; i < 4; ++i) {
        const int k = kbase + ((0 * 4 + i + rot) & 127);
        bA[i] = Mp4[(size_t)k * 32 + cg];
    }
    #pragma unroll
    for (int g = 0; g < 32; ++g) {
        float4* cur = (g & 1) ? bB : bA;
        float4* nxt = (g & 1) ? bA : bB;
        if (g < 31) {
            #pragma unroll
            for (int i = 0; i < 4; ++i) {
                const int k = kbase + ((g * 4 + 4 + i + rot) & 127);
                nxt[i] = Mp4[(size_t)k * 32 + cg];
            }
        }
        #pragma unroll
        for (int i = 0; i < 4; ++i) {
            const int k = kbase + ((g * 4 + i + rot) & 127);
            const float4 mv = cur[i];
            #pragma unroll
            for (int r = 0; r < 8; ++r) {
                const float sv = s_lds[r * 1024 + k];
                acc[r].x = fmaf(sv, mv.x, acc[r].x);
                acc[r].y = fmaf(sv, mv.y, acc[r].y);
                acc[r].z = fmaf(sv, mv.z, acc[r].z);
                acc[r].w = fmaf(sv, mv.w, acc[r].w);
            }
        }
    }
    __syncthreads();
    float* part = s_lds;
    #pragma unroll
    for (int r = 0; r < 8; ++r)
        *reinterpret_cast<float4*>(&part[(kg * 8 + r) * 128 + c4]) = acc[r];
    __syncthreads();

    {
        const int r = tid >> 5;
        float4 sum = make_float4(0.f, 0.f, 0.f, 0.f);
        #pragma unroll
        for (int g = 0; g < 8; ++g) {
            const float4 p = *reinterpret_cast<const float4*>(&part[(g * 8 + r) * 128 + c4]);
            sum.x += p.x; sum.y += p.y; sum.z += p.z; sum.w += p.w;
        }
        *reinterpret_cast<float4*>(out + (rb + r) * D + c4) = sum;
    }
}

} // namespace

extern "C" void kernel_launch(void* const* d_in, const int* in_sizes, int n_in,
                              void* d_out, int out_size, void* d_ws, size_t ws_size,
                              hipStream_t stream) {
    const float* center    = (const float*)d_in[0];
    const float* neighbors = (const float*)d_in[1];
    const float* WQ        = (const float*)d_in[2];
    const float* WK        = (const float*)d_in[3];
    const float* WV        = (const float*)d_in[4];
    const float* WO        = (const float*)d_in[5];
    float* outp            = (float*)d_out;

    const int B = in_sizes[0] / D;   // 8192

    float* Nmat = (float*)d_ws;                 // 128*1024
    float* Mmat = Nmat + 128 * 1024;            // 1024*128
    float* QS   = Mmat + 1024 * 128;            // B*1024 (qk, then s in-place)

    hipLaunchKernelGGL(k0_nm,    dim3(512),          dim3(256), 0, stream, WQ, WK, WV, WO, Nmat, Mmat);
    hipLaunchKernelGGL(k1_qk,    dim3(B / 8),        dim3(256), 0, stream, center, Nmat, QS);
    hipLaunchKernelGGL(k2_stream,dim3(B / K2_ITERS), dim3(256), 0, stream, center, neighbors, QS);
    hipLaunchKernelGGL(k3_out,   dim3(B / 8),        dim3(256), 0, stream, QS, Mmat, outp);
}

// Round 9
// 143.480 us; speedup vs baseline: 1.6468x; 1.6468x over previous
//
#include <hip/hip_runtime.h>
#include <math.h>

namespace {

constexpr int D  = 128;
constexpr int H  = 8;
constexpr int TN = 64;

// d_ws layout (requires ws_size >= 34.6 MB):
//   N  [128][1024] f32, M [1024][128] f32, QS [B][1024] f32 (qk -> s in-place)

// ---------------- K0: precompute N and M (tiny) ----------------
__global__ __launch_bounds__(256)
void k0_nm(const float* __restrict__ WQ, const float* __restrict__ WK,
           const float* __restrict__ WV, const float* __restrict__ WO,
           float* __restrict__ Nmat, float* __restrict__ Mmat)
{
    const int t = blockIdx.x * 256 + threadIdx.x;   // 0..131071
    {
        const int k = t >> 10, col = t & 1023;
        const int h = col >> 7, d = col & 127;
        const float* wq = WQ + (size_t)k * D + h * 16;
        const float* wk = WK + (size_t)d * D + h * 16;
        float a = 0.f;
        #pragma unroll
        for (int j = 0; j < 16; ++j) a = fmaf(wq[j], wk[j], a);
        Nmat[t] = 0.25f * a;
    }
    {
        const int row = t >> 7, e = t & 127;
        const int h = row >> 7, d = row & 127;
        const float* wv = WV + (size_t)d * D + h * 16;
        const float* wo = WO + (size_t)(h * 16) * D + e;
        float a = 0.f;
        #pragma unroll
        for (int j = 0; j < 16; ++j) a = fmaf(wv[j], wo[(size_t)j * D], a);
        Mmat[t] = a;
    }
}

// ---------------- K1: qk = center @ N  (8 rows/block, proven) ----------------
__global__ __launch_bounds__(256)
void k1_qk(const float* __restrict__ center, const float* __restrict__ Nmat,
           float* __restrict__ qk)
{
    __shared__ float c_lds[8 * 128];
    const int tid = threadIdx.x;
    const size_t rb = (size_t)blockIdx.x * 8;

    ((float4*)c_lds)[tid] = ((const float4*)(center + rb * D))[tid];
    __syncthreads();

    const float4* Np = (const float4*)Nmat + tid;
    float4 acc[8];
    #pragma unroll
    for (int r = 0; r < 8; ++r) acc[r] = make_float4(0.f, 0.f, 0.f, 0.f);

    float4 bufA[4], bufB[4];
    #pragma unroll
    for (int i = 0; i < 4; ++i) bufA[i] = Np[(size_t)i * 256];

    #pragma unroll
    for (int g = 0; g < 32; ++g) {
        float4* cur = (g & 1) ? bufB : bufA;
        float4* nxt = (g & 1) ? bufA : bufB;
        if (g < 31) {
            #pragma unroll
            for (int i = 0; i < 4; ++i) nxt[i] = Np[(size_t)(g * 4 + 4 + i) * 256];
        }
        #pragma unroll
        for (int i = 0; i < 4; ++i) {
            const int k = g * 4 + i;
            const float4 nv = cur[i];
            #pragma unroll
            for (int r = 0; r < 8; ++r) {
                const float cc = c_lds[r * 128 + k];
                acc[r].x = fmaf(cc, nv.x, acc[r].x);
                acc[r].y = fmaf(cc, nv.y, acc[r].y);
                acc[r].z = fmaf(cc, nv.z, acc[r].z);
                acc[r].w = fmaf(cc, nv.w, acc[r].w);
            }
        }
    }
    #pragma unroll
    for (int r = 0; r < 8; ++r)
        ((float4*)(qk + (rb + r) * 1024))[tid] = acc[r];
}

// ---------------- K2 v6: r7 shell + DS-op diet ----------------
// LDS 40.5 KB -> 4 blocks/CU. One softmax reduce (wave 0); shfl-free pass 2.
__global__ __launch_bounds__(256)
void k2_stream(const float* __restrict__ center, const float* __restrict__ neighbors,
               float* __restrict__ qs /* in: qk, out: s (in-place per batch) */)
{
    __shared__ float nb_lds[TN * 32 * 4];  // 32 KB; f4 slot (t<<5)|(fc^(t&7))
    __shared__ float qk_lds[H * 128];      // 4 KB
    __shared__ float sp_lds[768];          // 3 KB union: S[8][68] then P[64][12]
    __shared__ float c_lds[D];             // 0.5 KB
    __shared__ float red_m[8], red_inv[8], red_pc[8];

    const int tid = threadIdx.x;           // 0..255
    const int w   = tid >> 6;              // wave 0..3
    const int l   = tid & 63;
    const int b   = blockIdx.x;

    float*        qsb = qs + (size_t)b * 1024;
    const float4* gnb = (const float4*)(neighbors + (size_t)b * TN * D);
    float4*       nb4 = (float4*)nb_lds;
    const float4* qk4 = (const float4*)qk_lds;
    float4*       P4  = (float4*)sp_lds;
    const float4* c4  = (const float4*)c_lds;

    // ---- stage (r7-proven): 8 f4/thread coalesced -> swizzled LDS ----
    float4 st[8];
    #pragma unroll
    for (int i = 0; i < 8; ++i) st[i] = gnb[i * 256 + tid];
    const float4 qv = ((const float4*)qsb)[tid];
    float4 cv;
    if (tid < 32) cv = ((const float4*)(center + (size_t)b * D))[tid];

    #pragma unroll
    for (int i = 0; i < 8; ++i) {
        const int fi = i * 256 + tid;
        const int t  = fi >> 5;
        const int fc = fi & 31;
        nb4[(t << 5) | (fc ^ (t & 7))] = st[i];
    }
    ((float4*)qk_lds)[tid] = qv;           // linear [h][fc]
    if (tid < 32) ((float4*)c_lds)[tid] = cv;
    __syncthreads();

    // ---- phase A: scores. wave w -> tokens w*16+tq; quarters q split d ----
    const int tq = l & 15;
    const int q  = l >> 4;
    const int t1 = w * 16 + tq;
    const int t1rb = t1 << 5;
    const int t1sw = t1 & 7;
    float sc[8];
    #pragma unroll
    for (int h = 0; h < 8; ++h) sc[h] = 0.f;
    #pragma unroll
    for (int jj = 0; jj < 8; ++jj) {
        const int fc = q * 8 + ((jj + q) & 7);   // quarters hit distinct bank-quads
        const float4 tv = nb4[t1rb | (fc ^ t1sw)];
        #pragma unroll
        for (int h = 0; h < 8; ++h) {
            const float4 kv = qk4[h * 32 + fc];
            sc[h] = fmaf(tv.x, kv.x, fmaf(tv.y, kv.y, fmaf(tv.z, kv.z, fmaf(tv.w, kv.w, sc[h]))));
        }
    }
    #pragma unroll
    for (int h = 0; h < 8; ++h) {          // combine 4 d-quarters
        sc[h] += __shfl_xor(sc[h], 16);
        sc[h] += __shfl_xor(sc[h], 32);
    }
    if (l < 16) {                          // q==0 lanes publish scores: S[h][t]
        #pragma unroll
        for (int h = 0; h < 8; ++h) sp_lds[h * 68 + t1] = sc[h];
    }
    __syncthreads();

    // ---- phase B: wave 0 alone: s0 + softmax reduction ----
    if (w == 0) {
        const int h  = l & 7;
        const int sl = l >> 3;             // slot 0..7
        // s0 partial: qk[h][sl*16..+16] . c[sl*16..+16]
        float s0 = 0.f;
        #pragma unroll
        for (int i = 0; i < 4; ++i) {
            const float4 kq = qk4[h * 32 + sl * 4 + i];
            const float4 cc = c4[sl * 4 + i];
            s0 = fmaf(kq.x, cc.x, fmaf(kq.y, cc.y, fmaf(kq.z, cc.z, fmaf(kq.w, cc.w, s0))));
        }
        s0 += __shfl_xor(s0, 8);
        s0 += __shfl_xor(s0, 16);
        s0 += __shfl_xor(s0, 32);          // all lanes: s0 for their h
        // max over 64 token-scores + s0
        float sv[8];
        float m = s0;
        #pragma unroll
        for (int k = 0; k < 8; ++k) {
            sv[k] = sp_lds[h * 68 + sl * 8 + k];
            m = fmaxf(m, sv[k]);
        }
        m = fmaxf(m, __shfl_xor(m, 8));
        m = fmaxf(m, __shfl_xor(m, 16));
        m = fmaxf(m, __shfl_xor(m, 32));
        // sum of exps
        float s = 0.f;
        #pragma unroll
        for (int k = 0; k < 8; ++k) s += __expf(sv[k] - m);
        s += __shfl_xor(s, 8);
        s += __shfl_xor(s, 16);
        s += __shfl_xor(s, 32);
        const float e0  = __expf(s0 - m);
        const float inv = 1.0f / (s + e0);
        if (sl == 0) {                     // lanes 0..7 publish
            red_m[h]   = m;
            red_inv[h] = inv;
            red_pc[h]  = e0 * inv;
        }
    }
    __syncthreads();

    // ---- phase C: all waves: pmy from registers; write P[64][12] (padded) ----
    if (l < 16) {
        float pmy[8];
        #pragma unroll
        for (int h = 0; h < 8; ++h)
            pmy[h] = __expf(sc[h] - red_m[h]) * red_inv[h];
        P4[t1 * 3]     = make_float4(pmy[0], pmy[1], pmy[2], pmy[3]);
        P4[t1 * 3 + 1] = make_float4(pmy[4], pmy[5], pmy[6], pmy[7]);
    }
    __syncthreads();

    // ---- phase D: pass 2, shfl-free. wave w: its 16 tokens; lane=(h-half, col) ----
    const int hl = l >> 5;                 // h half: h = hl*4..hl*4+3
    const int fc = l & 31;                 // f4 column
    float4 acc[4];
    #pragma unroll
    for (int j = 0; j < 4; ++j) acc[j] = make_float4(0.f, 0.f, 0.f, 0.f);
    #pragma unroll
    for (int tt = 0; tt < 16; ++tt) {
        const int t = w * 16 + tt;
        const float4 tv = nb4[(t << 5) | (fc ^ (t & 7))];   // 32 distinct cols: conflict-free
        const float4 pv = P4[t * 3 + hl];                   // 2 addrs, broadcast
        acc[0].x = fmaf(pv.x, tv.x, acc[0].x); acc[0].y = fmaf(pv.x, tv.y, acc[0].y);
        acc[0].z = fmaf(pv.x, tv.z, acc[0].z); acc[0].w = fmaf(pv.x, tv.w, acc[0].w);
        acc[1].x = fmaf(pv.y, tv.x, acc[1].x); acc[1].y = fmaf(pv.y, tv.y, acc[1].y);
        acc[1].z = fmaf(pv.y, tv.z, acc[1].z); acc[1].w = fmaf(pv.y, tv.w, acc[1].w);
        acc[2].x = fmaf(pv.z, tv.x, acc[2].x); acc[2].y = fmaf(pv.z, tv.y, acc[2].y);
        acc[2].z = fmaf(pv.z, tv.z, acc[2].z); acc[2].w = fmaf(pv.z, tv.w, acc[2].w);
        acc[3].x = fmaf(pv.w, tv.x, acc[3].x); acc[3].y = fmaf(pv.w, tv.y, acc[3].y);
        acc[3].z = fmaf(pv.w, tv.z, acc[3].z); acc[3].w = fmaf(pv.w, tv.w, acc[3].w);
    }
    // write partials into this wave's OWN (now dead) nb rows: slot w*512 + h*33 + fc
    #pragma unroll
    for (int j = 0; j < 4; ++j) {
        const int h = hl * 4 + j;
        nb4[w * 512 + h * 33 + fc] = acc[j];
    }
    __syncthreads();

    // ---- phase E: combine 4 wave-partials + center seed; coalesced global write ----
    {
        const int h  = tid >> 5;           // 0..7
        const int f  = tid & 31;           // f4 col
        float4 sum = make_float4(0.f, 0.f, 0.f, 0.f);
        #pragma unroll
        for (int ww = 0; ww < 4; ++ww) {
            const float4 p = nb4[ww * 512 + h * 33 + f];
            sum.x += p.x; sum.y += p.y; sum.z += p.z; sum.w += p.w;
        }
        const float pc = red_pc[h];
        const float4 cc = c4[f];
        sum.x = fmaf(pc, cc.x, sum.x);
        sum.y = fmaf(pc, cc.y, sum.y);
        sum.z = fmaf(pc, cc.z, sum.z);
        sum.w = fmaf(pc, cc.w, sum.w);
        ((float4*)qsb)[tid] = sum;         // qsb[h*128 + f*4 ..] == f4 index tid
    }
}

// ---------------- K3: out = s @ M  (8 rows/block, proven) ----------------
__global__ __launch_bounds__(256)
void k3_out(const float* __restrict__ qs, const float* __restrict__ Mmat,
            float* __restrict__ out)
{
    __shared__ float s_lds[8 * 1024];
    const int tid = threadIdx.x;
    const size_t rb = (size_t)blockIdx.x * 8;

    {
        const float4* sp = (const float4*)(qs + rb * 1024);
        #pragma unroll
        for (int i = 0; i < 8; ++i)
            ((float4*)s_lds)[i * 256 + tid] = sp[i * 256 + tid];
    }
    __syncthreads();

    const int cg = tid & 31;
    const int kg = tid >> 5;
    const int c4 = cg << 2;
    const int kbase = kg << 7;
    const int rot = kg << 2;

    float4 acc[8];
    #pragma unroll
    for (int r = 0; r < 8; ++r) acc[r] = make_float4(0.f, 0.f, 0.f, 0.f);

    const float4* Mp4 = (const float4*)Mmat;

    float4 bA[4], bB[4];
    #pragma unroll
    for (int i = 0; i < 4; ++i) {
        const int k = kbase + ((0 * 4 + i + rot) & 127);
        bA[i] = Mp4[(size_t)k * 32 + cg];
    }
    #pragma unroll
    for (int g = 0; g < 32; ++g) {
        float4* cur = (g & 1) ? bB : bA;
        float4* nxt = (g & 1) ? bA : bB;
        if (g < 31) {
            #pragma unroll
            for (int i = 0; i < 4; ++i) {
                const int k = kbase + ((g * 4 + 4 + i + rot) & 127);
                nxt[i] = Mp4[(size_t)k * 32 + cg];
            }
        }
        #pragma unroll
        for (int i = 0; i < 4; ++i) {
            const int k = kbase + ((g * 4 + i + rot) & 127);
            const float4 mv = cur[i];
            #pragma unroll
            for (int r = 0; r < 8; ++r) {
                const float sv = s_lds[r * 1024 + k];
                acc[r].x = fmaf(sv, mv.x, acc[r].x);
                acc[r].y = fmaf(sv, mv.y, acc[r].y);
                acc[r].z = fmaf(sv, mv.z, acc[r].z);
                acc[r].w = fmaf(sv, mv.w, acc[r].w);
            }
        }
    }
    __syncthreads();
    float* part = s_lds;
    #pragma unroll
    for (int r = 0; r < 8; ++r)
        *reinterpret_cast<float4*>(&part[(kg * 8 + r) * 128 + c4]) = acc[r];
    __syncthreads();

    {
        const int r = tid >> 5;
        float4 sum = make_float4(0.f, 0.f, 0.f, 0.f);
        #pragma unroll
        for (int g = 0; g < 8; ++g) {
            const float4 p = *reinterpret_cast<const float4*>(&part[(g * 8 + r) * 128 + c4]);
            sum.x += p.x; sum.y += p.y; sum.z += p.z; sum.w += p.w;
        }
        *reinterpret_cast<float4*>(out + (rb + r) * D + c4) = sum;
    }
}

} // namespace

extern "C" void kernel_launch(void* const* d_in, const int* in_sizes, int n_in,
                              void* d_out, int out_size, void* d_ws, size_t ws_size,
                              hipStream_t stream) {
    const float* center    = (const float*)d_in[0];
    const float* neighbors = (const float*)d_in[1];
    const float* WQ        = (const float*)d_in[2];
    const float* WK        = (const float*)d_in[3];
    const float* WV        = (const float*)d_in[4];
    const float* WO        = (const float*)d_in[5];
    float* outp            = (float*)d_out;

    const int B = in_sizes[0] / D;   // 8192

    float* Nmat = (float*)d_ws;                 // 128*1024
    float* Mmat = Nmat + 128 * 1024;            // 1024*128
    float* QS   = Mmat + 1024 * 128;            // B*1024 (qk, then s in-place)

    hipLaunchKernelGGL(k0_nm,    dim3(512),   dim3(256), 0, stream, WQ, WK, WV, WO, Nmat, Mmat);
    hipLaunchKernelGGL(k1_qk,    dim3(B / 8), dim3(256), 0, stream, center, Nmat, QS);
    hipLaunchKernelGGL(k2_stream,dim3(B),     dim3(256), 0, stream, center, neighbors, QS);
    hipLaunchKernelGGL(k3_out,   dim3(B / 8), dim3(256), 0, stream, QS, Mmat, outp);
}